// Round 5
// baseline (156.945 us; speedup 1.0000x reference)
//
#include <hip/hip_runtime.h>

// LocallyConnected1d via bf16 MFMA: out[b,o,l] = sum_{i,k} x[b,i,l+k-4]*w[i,o,k,l] + bias[o,l]
// 512 per-l GEMMs (M=b, N=o (8 real, 8 zero-padded), K=576 k-major).
//
// R13: two TRULY co-resident blocks per CU (R12 post-mortem: 4 structural
// changes neutral; all pipes <35% busy; single 16-wave barrier domain runs
// its phases in lockstep bursts -> pipes used in sequence, not parallel.
// R11's half-block streamed weights 1.5x faster per CU but failed to
// co-schedule at exactly 2x81920 = capacity).
//  * BB=32 b per block, 512 thr (8 waves), grid 512 = lt*16 + bh*8 + os
//    (mod-8 = XCD preserved: bh pairs +-8, lt line-mates +-16 co-XCD).
//  * LDS trimmed to 76352 B (2x = 152.7 KB, 11 KB slack -- R11 lesson:
//    exact-capacity packing fails): XBS 40->36 (A-read stride 18 banks ->
//    16 distinct banks, conflict-free; saves 4.5 KB), BLS=328, 32-ush zeros.
//  * R10's verified schedule verbatim: 18 single-tap steps, 3-slot ring,
//    2 Bs parity buffers, lgkm-only BAR().
//  * R12's ks-rotation kept in STAGE_XS/DO_MFMA (stage-write conflict fix;
//    XLW=1152 ush is still 0 mod 32 banks without it).
//  * T5 setprio(1) around MFMA: with 2 independent blocks/CU there is
//    finally wave role diversity for the CU scheduler to arbitrate.

#define CIN   64
#define COUT  64
#define SEQ   512
#define KS    9
#define LT    16
#define OT    8
#define LWIN  24
#define BB    32                       // b per block
#define WSTR  (COUT*KS*SEQ)            // weight i-stride (floats)
#define XBS   36                       // Xs b-stride (ush): 32 i + 4 pad (18-bank stride: 16 lanes -> 16 banks)
#define XLW   (BB*XBS)                 // Xs lw-stride = 1152 ush
#define XS_ELEMS (LWIN*XLW)            // 27648 ush = 55296 B
#define BOS   40                       // Bs o-stride (ush)
#define BLS   328                      // Bs l-stride (ush)
#define BSLOT (LT*BLS)                 // 5248 ush per buffer
#define ZOFF  (XS_ELEMS + 2*BSLOT)     // 38144: zero region for n>=8 B reads
#define LDS_USH (ZOFF + 32)            // 38176 ush
#define LDS_BYTES (LDS_USH*2)          // 76352 B -> 2 blocks/CU (152.7 KB)
#define NSTEP 18                       // 2 i-halves x 9 k-taps

typedef __attribute__((ext_vector_type(8))) short bf16x8;
typedef __attribute__((ext_vector_type(4))) float f32x4;

__device__ __forceinline__ uint pack2bf(float a0, float a1) {
    uint u0 = __float_as_uint(a0) + 0x8000u;
    uint u1 = __float_as_uint(a1) + 0x8000u;
    return __builtin_amdgcn_perm(u1, u0, 0x07060302);  // (bf(a1)<<16)|bf(a0)
}

// Relaxed barrier: drain LDS only; global loads stay in flight across it.
#define BAR() do {                                                           \
    asm volatile("s_waitcnt lgkmcnt(0)" ::: "memory");                       \
    __builtin_amdgcn_s_barrier();                                            \
    asm volatile("" ::: "memory");                                           \
} while (0)

__global__ __launch_bounds__(512, 4)
void lc1d_mfma(const float* __restrict__ x, const float* __restrict__ w,
               const float* __restrict__ bias, float* __restrict__ out)
{
    extern __shared__ ushort lds[];
    ushort* Xs = lds;                    // [lw 0..23][b 0..31][ks-rotated 32 + 4 pad]
    ushort* BsB = lds + XS_ELEMS;        // 2 x [l 0..15][o 0..7][kk 0..31]

    const int tid  = threadIdx.x;
    const int lane = tid & 63;
    const int wvid = tid >> 6;           // 0..7
    const int bt = wvid & 1;             // wave's b-tile (16 b)
    const int lg = wvid >> 1;            // wave's l-group (4 l)
    const int lt = blockIdx.x >> 4;      // 0..31
    const int bh = (blockIdx.x >> 3) & 1;// b-half
    const int os = blockIdx.x & 7;       // 0..7 == XCD id
    const int l0 = lt * LT;
    const int o0 = os * OT;

    // ---- weight stager mapping (all 512 threads): 64-B-contiguous l spans --
    const int lf  = tid & 3;             // float4 within the 16-l span
    const int oo  = (tid >> 2) & 7;      // o
    const int ipp = (tid >> 5) & 15;     // i-pair within 32-i half

    const float* wbase = w + ((size_t)(2*ipp)*COUT + (o0 + oo))*(KS*SEQ) + l0 + lf*4;

    float4 rA[3], rB[3];                 // 3-slot ring, i-pair per slot

    // step s: ih = s/9 (i-half), k = s%9 (tap)
    #define LOAD_RING(sl, s) if ((s) < NSTEP) {                                  \
        const int ih_ = (s) / 9, k_ = (s) - 9*ih_;                               \
        const float* p_ = wbase + (size_t)ih_*32*WSTR + k_*SEQ;                  \
        rA[sl] = *(const float4*)p_;                                             \
        rB[sl] = *(const float4*)(p_ + WSTR);                                    \
    }

    // transpose+cvt ring slot -> Bs parity (s&1): b32 of i-pair at [l][o][kk]
    #define WRITE_BS(sl, s) {                                                    \
        ushort* dst_ = BsB + ((s)&1)*BSLOT + oo*BOS + 2*ipp;                     \
        _Pragma("unroll")                                                        \
        for (int dl = 0; dl < 4; ++dl) {                                         \
            uint pk_ = pack2bf((&rA[sl].x)[dl], (&rB[sl].x)[dl]);                \
            *(uint*)(dst_ + (lf*4+dl)*BLS) = pk_;                                \
        }                                                                        \
    }

    // stage Xs for i-half ih: Xs[lw][b][rot(ii)] = bf16(x[bh*32+b, ih*32+ii, l0-4+lw])
    // rot: row lw = qq*4+dl keeps its four 8-ush ks-groups rotated by qq&3
    // (= (row>>2)&3), matching the read-side col formula below.
    #define STAGE_XS(ih) {                                                       \
        const int qq  = tid & 7;                                                 \
        const int rp0 = tid >> 3;                                                \
        const int cr_ = (qq & 3) << 3;                                           \
        if (qq < 6) {                                                            \
            _Pragma("unroll")                                                    \
            for (int it = 0; it < 8; ++it) {                                     \
                const int rp = rp0 + it*64;                                      \
                const int b_ = rp >> 4, ip_ = rp & 15;                           \
                const float* s0 = x + ((size_t)((bh*BB + b_)*CIN) + (ih)*32      \
                                       + 2*ip_)*SEQ + (l0 - 4) + qq*4;           \
                float4 v0 = make_float4(0.f,0.f,0.f,0.f), v1 = v0;               \
                if (!((lt == 0 && qq == 0) || (lt == 31 && qq == 5))) {          \
                    v0 = *(const float4*)s0;                                     \
                    v1 = *(const float4*)(s0 + SEQ);                             \
                }                                                                \
                ushort* d_ = Xs + b_*XBS + ((2*ip_ + cr_) & 31);                 \
                _Pragma("unroll")                                                \
                for (int dl = 0; dl < 4; ++dl)                                   \
                    *(uint*)(d_ + (qq*4+dl)*XLW) = pack2bf((&v0.x)[dl],          \
                                                           (&v1.x)[dl]);         \
            }                                                                    \
        }                                                                        \
    }

    // MFMA lane constants
    const int abase = (bt*16 + (lane & 15))*XBS;
    const int ks_   = lane >> 4;
    const int boff  = (lane & 15)*BOS + ks_*8;
    const bool nhi  = (lane & 15) >= 8;                // dead o lanes -> zeros
    const ushort* zptr = lds + ZOFF + ks_*8;           // broadcast zeros

    f32x4 acc[4];
    #pragma unroll
    for (int j = 0; j < 4; ++j) acc[j] = (f32x4)0.0f;

    #define DO_MFMA(s) {                                                         \
        const int k_ = (s) % 9;                                                  \
        const ushort* BsS = BsB + ((s)&1)*BSLOT;                                 \
        _Pragma("unroll")                                                        \
        for (int dl = 0; dl < 4; ++dl) {                                         \
            const int ll  = lg*4 + dl;                                           \
            const int row = ll + k_;                                             \
            const int col = ((ks_ + (row >> 2)) & 3) << 3;                       \
            bf16x8 Af = *(const bf16x8*)(Xs + row*XLW + abase + col);            \
            const ushort* Bp = nhi ? zptr : (BsS + ll*BLS + boff);               \
            bf16x8 Bf = *(const bf16x8*)Bp;                                      \
            acc[dl] = __builtin_amdgcn_mfma_f32_16x16x32_bf16(Af, Bf, acc[dl],   \
                                                              0, 0, 0);          \
        }                                                                        \
    }

    // one barrier per step: during step s, stagers fill Bs parity (s+1)&1.
    // setprio around MFMA: pays now that 2 blocks/CU give role diversity.
    #define STEP(s) {                                                            \
        if ((s) < NSTEP-1) WRITE_BS(((s)+1)%3, (s)+1)                            \
        LOAD_RING(((s)+1)%3, (s)+4)                                              \
        __builtin_amdgcn_s_setprio(1);                                           \
        DO_MFMA(s)                                                               \
        __builtin_amdgcn_s_setprio(0);                                           \
        BAR();                                                                   \
    }

    // ---- prologue ----
    LOAD_RING(0, 0)
    LOAD_RING(1, 1)
    LOAD_RING(2, 2)
    if (tid < 32) lds[ZOFF + tid] = 0;
    STAGE_XS(0)
    WRITE_BS(0, 0)
    LOAD_RING(0, 3)
    BAR();             // Xs(ih0) + Bs(step0) + zero region ready

    STEP(0)  STEP(1)  STEP(2)  STEP(3)  STEP(4)
    STEP(5)  STEP(6)  STEP(7)  STEP(8)

    STAGE_XS(1)        // all half-0 Xs reads completed at STEP(8)'s barrier
    BAR();

    STEP(9)  STEP(10) STEP(11) STEP(12) STEP(13)
    STEP(14) STEP(15) STEP(16) STEP(17)

    // ---- epilogue: C col = o' = lane&15 (store only o'<8), row = b_local ----
    if (!nhi) {
        const int og = o0 + (lane & 15);
        const int rb = ks_*4;
        #pragma unroll
        for (int dl = 0; dl < 4; ++dl) {
            const int lgl = l0 + lg*4 + dl;
            const float bv = bias[og*SEQ + lgl];
            #pragma unroll
            for (int r = 0; r < 4; ++r) {
                const int bg = bh*BB + bt*16 + rb + r;
                out[((size_t)(bg*COUT + og))*SEQ + lgl] = acc[dl][r] + bv;
            }
        }
    }
}

extern "C" void kernel_launch(void* const* d_in, const int* in_sizes, int n_in,
                              void* d_out, int out_size, void* d_ws, size_t ws_size,
                              hipStream_t stream) {
    const float* x    = (const float*)d_in[0];
    const float* wgt  = (const float*)d_in[1];
    const float* bias = (const float*)d_in[2];
    float* out        = (float*)d_out;

    hipFuncSetAttribute((const void*)lc1d_mfma,
                        hipFuncAttributeMaxDynamicSharedMemorySize, LDS_BYTES);
    dim3 grid(512);   // blockIdx = lt*16 + bh*8 + os: mod-8 = XCD preserved
    lc1d_mfma<<<grid, 512, LDS_BYTES, stream>>>(x, wgt, bias, out);
}